// Round 20
// baseline (1032.082 us; speedup 1.0000x reference)
//
#include <hip/hip_runtime.h>
#include <hip/hip_bf16.h>

#define B_  64
#define S_  128
#define WP_ 18
#define K_  3
#define E_  128
#define H_  256
#define L_  4
#define T_  50

typedef __hip_bfloat16 bf16;

__device__ __forceinline__ float b2f(bf16 x) { return __bfloat162float(x); }
__device__ __forceinline__ bf16  f2b(float x) { return __float2bfloat16(x); }

__device__ __forceinline__ float fast_sigmoid(float x) {
    return 1.f / (1.f + __expf(-x));
}
__device__ __forceinline__ float fast_tanh(float x) {
    float a = fminf(fmaxf(2.f * x, -30.f), 30.f);
    float e = __expf(a);
    return (e - 1.f) / (e + 1.f);
}
__device__ __forceinline__ unsigned int pack2(float lo, float hi) {
    bf16 l = f2b(lo), h = f2b(hi);
    unsigned short ls = *(unsigned short*)&l, hs = *(unsigned short*)&h;
    return ((unsigned int)hs << 16) | ls;
}

// v_dot2_f32_bf16: z += lo(w)*lo(h) + hi(w)*hi(h)
#define DOT2(z, w, h) asm("v_dot2_f32_bf16 %0, %1, %2, %0" : "+v"(z) : "v"(w), "v"(h))
// opaque pin: value becomes non-rematerializable
#define PIN4(V_) asm volatile("" : "+v"((V_).x), "+v"((V_).y), "+v"((V_).z), "+v"((V_).w))

// ---------------------------------------------------------------- prep: all weight repacks
// whh pack for 512-thread rec layout: thread u=i*2+p2, slice m2=g*16+kk2 (64 slices x 512 thr x 4 u32)
__global__ void k_prep(const float* __restrict__ whh_f, const float* __restrict__ whh_b,
                       const float* __restrict__ wih_f, const float* __restrict__ wih_b,
                       unsigned int* __restrict__ wp_f, unsigned int* __restrict__ wp_b,
                       unsigned int* __restrict__ wihT2_f, unsigned int* __restrict__ wihT2_b) {
    int blk = blockIdx.x, t = threadIdx.x;
    if (blk < 1024) {
        const float* src   = (blk < 512) ? whh_f : whh_b;
        unsigned int* dst  = (blk < 512) ? wp_f  : wp_b;
        int d = ((blk & 511) << 8) + t;            // u32 index over 1024*128
        int m2 = d >> 11, rem = d & 2047;
        int u = rem >> 2, e2 = rem & 3;
        int i = u >> 1, p2 = u & 1;
        int g = m2 >> 4, kk2 = m2 & 15;
        int col = (g << 8) + i;
        int k = (p2 << 7) + (kk2 << 3) + (e2 << 1);
        float2 sv = *(const float2*)(src + col * 256 + k);
        dst[d] = pack2(sv.x, sv.y);
    } else {
        int id = blk - 1024;
        const float* src  = (id < 256) ? wih_f   : wih_b;
        unsigned int* dst = (id < 256) ? wihT2_f : wihT2_b;
        int d = ((id & 255) << 8) + t;             // u32 index over 64*1024
        int kp = d >> 10, j = d & 1023;
        float2 sv = *(const float2*)(src + j * 128 + 2 * kp);
        dst[d] = pack2(sv.x, sv.y);                // wihT2[kp*1024 + j]
    }
}

// ---------------------------------------------------------------- input proj (DOT2, 32 rows/block, 512 thr)
__global__ void k_input_proj(const int* __restrict__ word_ids,
                             const float* __restrict__ word_emb,
                             const unsigned int* __restrict__ wihT2_f, const float* __restrict__ b_f,
                             const unsigned int* __restrict__ wihT2_b, const float* __restrict__ b_b,
                             bf16* __restrict__ igq_f, bf16* __restrict__ igq_b) {
    int dir = blockIdx.y;
    const unsigned int* wihT2 = dir ? wihT2_b : wihT2_f;
    const float* bb  = dir ? b_b   : b_f;
    bf16* igq        = dir ? igq_b : igq_f;
    __shared__ unsigned int x2[32][64];
    int t  = threadIdx.x;                  // 0..511
    int r0 = blockIdx.x * 32;
    for (int u = t; u < 32 * 64; u += 512) {
        int rr = u >> 6, ep = u & 63;
        int r = r0 + rr;
        int s = r >> 6, b = r & 63;
        int wid = word_ids[b * S_ + s];
        float2 ev = *(const float2*)(word_emb + (size_t)wid * E_ + 2 * ep);
        x2[rr][ep] = pack2(ev.x, ev.y);
    }
    __syncthreads();
    int j = t & 255, jh = t >> 8;          // thread covers cj = 2jh, 2jh+1
    float acc[2][32];
    #pragma unroll
    for (int c2 = 0; c2 < 2; ++c2) {
        float bv = bb[j + (2 * jh + c2) * 256];
        #pragma unroll
        for (int rr = 0; rr < 32; ++rr) acc[c2][rr] = bv;
    }
    for (int kp = 0; kp < 64; ++kp) {
        unsigned int wv0 = wihT2[kp * 1024 + j + (2 * jh) * 256];
        unsigned int wv1 = wihT2[kp * 1024 + j + (2 * jh + 1) * 256];
        #pragma unroll
        for (int rr = 0; rr < 32; ++rr) {
            unsigned int xp = x2[rr][kp];
            DOT2(acc[0][rr], wv0, xp);
            DOT2(acc[1][rr], wv1, xp);
        }
    }
    #pragma unroll
    for (int rr = 0; rr < 32; ++rr)
        *(unsigned int*)(igq + (size_t)(r0 + rr) * 1024 + j * 4 + 2 * jh) =
            pack2(acc[0][rr], acc[1][rr]);
}

// ---------------------------------------------------------------- fused recurrence + char CNN
// 512 threads, 2 waves/SIMD. Thread u = i*2 + p2 covers unit i's 4 gate columns
// over k in [128*p2, 128*p2+128).
// Weights: m2=0..55 pinned in 224 regs (AGPR side), m2=56..63 in LDS (64 KB).
// 64-slice full pin SPILLS (round 19: +scratch traffic, 454 us) — 56 is the max.
__global__ __launch_bounds__(512, 2) void k_lstm_cnn(
        const bf16* __restrict__ igq_f, const bf16* __restrict__ igq_b,
        const uint4* __restrict__ wp_f, const uint4* __restrict__ wp_b,
        unsigned int* __restrict__ hfp, unsigned int* __restrict__ hbp,
        const int* __restrict__ char_ids, const float* __restrict__ char_emb,
        const float* __restrict__ cnn_w, const float* __restrict__ cnn_b,
        float* __restrict__ out_char) {
    __shared__ uint4 wlds[9216];                          // 144 KiB pool (rec uses 64 KiB)
    __shared__ __align__(16) unsigned int hpbuf[2][160];

    int t = threadIdx.x;

    if (blockIdx.x < 128) {
        // ======================= LSTM recurrence ==========================
        int b   = blockIdx.x & 63;
        int dir = blockIdx.x >> 6;
        const bf16* igq  = dir ? igq_b : igq_f;
        const uint4* wp  = dir ? wp_b  : wp_f;
        unsigned int* hs = dir ? hbp   : hfp;

        int i = t >> 1, p2 = t & 1;

        for (int v = t; v < 4096; v += 512) wlds[v] = wp[56 * 512 + v];
        if (t < 320) ((unsigned int*)hpbuf)[t] = 0;
        float c_reg = 0.f;

        uint4 wreg[56];
        #pragma unroll
        for (int m = 0; m < 56; ++m) {
            wreg[m] = wp[m * 512 + t];
            PIN4(wreg[m]);
        }
        __syncthreads();

        int cur = 0;
        int s0 = dir ? (S_ - 1) : 0;
        uint2 igu = *(const uint2*)&igq[((size_t)s0 * B_ + b) * 1024 + i * 4];

        for (int step = 0; step < S_; ++step) {
            int s = dir ? (S_ - 1 - step) : step;

            float z0 = 0.f, z1 = 0.f, z2 = 0.f, z3 = 0.f;
            if (p2 == 0) {
                z0 = __uint_as_float(igu.x << 16);
                z1 = __uint_as_float(igu.x & 0xffff0000u);
                z2 = __uint_as_float(igu.y << 16);
                z3 = __uint_as_float(igu.y & 0xffff0000u);
            }
            const char* hpc = (const char*)hpbuf[cur];
            #pragma unroll
            for (int kk = 0; kk < 16; ++kk) {
                uint4 hv = *(const uint4*)(hpc + (p2 * 2 + (kk >> 3)) * 144 + (kk & 7) * 16);
                {   uint4 wv = wreg[kk];
                    DOT2(z0, wv.x, hv.x); DOT2(z0, wv.y, hv.y);
                    DOT2(z0, wv.z, hv.z); DOT2(z0, wv.w, hv.w); }
                {   uint4 wv = wreg[16 + kk];
                    DOT2(z1, wv.x, hv.x); DOT2(z1, wv.y, hv.y);
                    DOT2(z1, wv.z, hv.z); DOT2(z1, wv.w, hv.w); }
                {   uint4 wv = wreg[32 + kk];
                    DOT2(z2, wv.x, hv.x); DOT2(z2, wv.y, hv.y);
                    DOT2(z2, wv.z, hv.z); DOT2(z2, wv.w, hv.w); }
                {   uint4 wv = (kk < 8) ? wreg[48 + kk] : wlds[(kk - 8) * 512 + t];
                    DOT2(z3, wv.x, hv.x); DOT2(z3, wv.y, hv.y);
                    DOT2(z3, wv.z, hv.z); DOT2(z3, wv.w, hv.w); }
            }
            if (step + 1 < S_) {
                int sn = dir ? (S_ - 2 - step) : (step + 1);
                igu = *(const uint2*)&igq[((size_t)sn * B_ + b) * 1024 + i * 4];
            }
            // butterfly over p2 only (lanes differing in bit 0)
            z0 += __shfl_xor(z0, 1);
            z1 += __shfl_xor(z1, 1);
            z2 += __shfl_xor(z2, 1);
            z3 += __shfl_xor(z3, 1);
            if (p2 == 0) {
                float si = fast_sigmoid(z0);
                float sf = fast_sigmoid(z1);
                float tg = fast_tanh(z2);
                float so = fast_sigmoid(z3);
                c_reg = sf * c_reg + si * tg;
                float hn = so * fast_tanh(c_reg);
                char* dstb = (char*)hpbuf[cur ^ 1] + (i >> 6) * 144 + ((i >> 1) & 31) * 4 + (i & 1) * 2;
                *(bf16*)dstb = f2b(hn);
            }
            __syncthreads();
            // export packed h (this step) to global, coalesced u32 stores
            if (t < 128) {
                hs[((size_t)s * B_ + b) * 128 + t] =
                    hpbuf[cur ^ 1][(t >> 5) * 36 + (t & 31)];
            }
            cur ^= 1;
        }
    } else {
        // ======================= char CNN on idle CUs ======================
        unsigned int* pool_u = (unsigned int*)wlds;
        float*        pool_f = (float*)wlds;
        int blkc = blockIdx.x - 128;

        for (int u = t; u < 4 * 192; u += 512) {
            int c = u / 192, pe = u % 192;
            pool_u[c * 196 + pe] = pack2(cnn_w[c * 384 + 2 * pe], cnn_w[c * 384 + 2 * pe + 1]);
        }
        if (t < 4) pool_f[784 + t] = cnn_b[t];
        __syncthreads();

        int wv = t >> 6, lane = t & 63;          // 8 waves
        unsigned int* cew = pool_u + 800 + wv * 1224;
        int pos = lane >> 2, c = lane & 3;

        #pragma unroll 1
        for (int j = 0; j < 8; ++j) {            // 8 words per wave
            int word = (blkc * 8 + wv) * 8 + j;
            const int* ids = char_ids + word * WP_;
            for (int row = 0; row < WP_; ++row) {
                float2 ev = *(const float2*)(char_emb + (size_t)ids[row] * 128 + 2 * lane);
                cew[row * 68 + lane] = pack2(ev.x, ev.y);
            }
            float acc = 0.f;
            #pragma unroll
            for (int i = 0; i < K_; ++i) {
                const uint4* cr = (const uint4*)(cew + (pos + i) * 68);
                const uint4* wr = (const uint4*)(pool_u + c * 196 + i * 64);
                #pragma unroll
                for (int q = 0; q < 16; ++q) {
                    uint4 cv = cr[q], wq = wr[q];
                    DOT2(acc, wq.x, cv.x); DOT2(acc, wq.y, cv.y);
                    DOT2(acc, wq.z, cv.z); DOT2(acc, wq.w, cv.w);
                }
            }
            acc += pool_f[784 + c];
            #pragma unroll
            for (int off = 4; off < 64; off <<= 1) acc = fmaxf(acc, __shfl_xor(acc, off));
            if (lane < L_) out_char[(size_t)word * L_ + lane] = acc;
        }
    }
}

// ---------------------------------------------------------------- fused tag linear + log_softmax
// one block per batch b; ow staged once; h in two 64-s chunks; tag scores in LDS;
// softmax over s in-LDS; direct write to out. LDS = 51400 + 65536 + 25600 = 142.5 KB.
__global__ __launch_bounds__(1024) void k_tag_sm(
        const unsigned int* __restrict__ hfp, const unsigned int* __restrict__ hbp,
        const float* __restrict__ out_w, const float* __restrict__ out_b,
        float* __restrict__ out) {
    __shared__ unsigned int ow[50 * 257];      // 51400 B
    __shared__ unsigned int hv[64][256];       // 65536 B
    __shared__ float tb[50][128];              // 25600 B
    int b = blockIdx.x;
    int t = threadIdx.x;                       // 0..1023

    for (int u = t; u < 12800; u += 1024) {
        int tt = u >> 8, kp = u & 255;
        float2 wv = *(const float2*)(out_w + tt * 512 + 2 * kp);
        ow[tt * 257 + kp] = pack2(wv.x, wv.y);
    }

    for (int chunk = 0; chunk < 2; ++chunk) {
        int sbase = chunk * 64;
        __syncthreads();                       // hv safe to overwrite (and ow ready, 1st iter)
        for (int u = t; u < 64 * 256; u += 1024) {
            int sl = u >> 8, q = u & 255;
            int s = sbase + sl;
            const unsigned int* src = (q < 128) ? hfp : hbp;
            hv[sl][q] = src[((size_t)s * B_ + b) * 128 + (q & 127)];
        }
        __syncthreads();
        for (int u = t; u < 50 * 64; u += 1024) {
            int tt = u >> 6, sl = u & 63;
            float acc = out_b[tt];
            const unsigned int* owr = &ow[tt * 257];
            const unsigned int* hvr = hv[sl];
            #pragma unroll 8
            for (int kp = 0; kp < 256; ++kp) DOT2(acc, owr[kp], hvr[kp]);
            tb[tt][sbase + sl] = acc;
        }
    }
    __syncthreads();

    // log_softmax over s (axis=1): 16 waves cover 50 t-rows
    int wv = t >> 6, lane = t & 63;
    for (int row = wv; row < T_; row += 16) {
        float v0 = tb[row][lane], v1 = tb[row][lane + 64];
        float m = fmaxf(v0, v1);
        #pragma unroll
        for (int off = 32; off; off >>= 1) m = fmaxf(m, __shfl_xor(m, off));
        float e = expf(v0 - m) + expf(v1 - m);
        #pragma unroll
        for (int off = 32; off; off >>= 1) e += __shfl_xor(e, off);
        float lse = m + logf(e);
        out[((size_t)b * S_ + lane)      * T_ + row] = v0 - lse;
        out[((size_t)b * S_ + lane + 64) * T_ + row] = v1 - lse;
    }
}

// ---------------------------------------------------------------- launch
extern "C" void kernel_launch(void* const* d_in, const int* in_sizes, int n_in,
                              void* d_out, int out_size, void* d_ws, size_t ws_size,
                              hipStream_t stream) {
    const int*   char_ids = (const int*)d_in[0];
    const int*   word_ids = (const int*)d_in[1];
    const float* char_emb = (const float*)d_in[2];
    const float* word_emb = (const float*)d_in[3];
    const float* cnn_w    = (const float*)d_in[4];
    const float* cnn_b    = (const float*)d_in[5];
    const float* wih_f    = (const float*)d_in[6];
    const float* whh_f    = (const float*)d_in[7];
    const float* b_f      = (const float*)d_in[8];
    const float* wih_b    = (const float*)d_in[9];
    const float* whh_b    = (const float*)d_in[10];
    const float* b_b      = (const float*)d_in[11];
    const float* out_w    = (const float*)d_in[12];
    const float* out_b    = (const float*)d_in[13];
    float* out = (float*)d_out;
    char* ws   = (char*)d_ws;

    size_t o = 0;
    unsigned int* wihT2_f = (unsigned int*)(ws + o); o += (size_t)64 * 1024 * 4;
    unsigned int* wihT2_b = (unsigned int*)(ws + o); o += (size_t)64 * 1024 * 4;
    unsigned int* wp_f    = (unsigned int*)(ws + o); o += (size_t)1024 * 128 * 4;
    unsigned int* wp_b    = (unsigned int*)(ws + o); o += (size_t)1024 * 128 * 4;
    bf16* igq_f  = (bf16*)(ws + o); o += (size_t)S_ * B_ * 1024 * 2;
    bf16* igq_b  = (bf16*)(ws + o); o += (size_t)S_ * B_ * 1024 * 2;
    unsigned int* hfp = (unsigned int*)(ws + o); o += (size_t)S_ * B_ * 128 * 4;
    unsigned int* hbp = (unsigned int*)(ws + o); o += (size_t)S_ * B_ * 128 * 4;

    k_prep<<<1536, 256, 0, stream>>>(whh_f, whh_b, wih_f, wih_b,
                                     wp_f, wp_b, wihT2_f, wihT2_b);
    k_input_proj<<<dim3(256, 2), 512, 0, stream>>>(word_ids, word_emb,
                                                   wihT2_f, b_f, wihT2_b, b_b, igq_f, igq_b);
    k_lstm_cnn<<<256, 512, 0, stream>>>(igq_f, igq_b,
                                        (const uint4*)wp_f, (const uint4*)wp_b, hfp, hbp,
                                        char_ids, char_emb, cnn_w, cnn_b,
                                        out + (size_t)B_ * S_ * T_);
    k_tag_sm<<<B_, 1024, 0, stream>>>(hfp, hbp, out_w, out_b, out);
}

// Round 21
// 386.859 us; speedup vs baseline: 2.6679x; 2.6679x over previous
//
#include <hip/hip_runtime.h>
#include <hip/hip_bf16.h>

#define B_  64
#define S_  128
#define WP_ 18
#define K_  3
#define E_  128
#define H_  256
#define L_  4
#define T_  50

typedef __hip_bfloat16 bf16;

__device__ __forceinline__ float b2f(bf16 x) { return __bfloat162float(x); }
__device__ __forceinline__ bf16  f2b(float x) { return __float2bfloat16(x); }

__device__ __forceinline__ float fast_sigmoid(float x) {
    return 1.f / (1.f + __expf(-x));
}
__device__ __forceinline__ float fast_tanh(float x) {
    float a = fminf(fmaxf(2.f * x, -30.f), 30.f);
    float e = __expf(a);
    return (e - 1.f) / (e + 1.f);
}
__device__ __forceinline__ unsigned int pack2(float lo, float hi) {
    bf16 l = f2b(lo), h = f2b(hi);
    unsigned short ls = *(unsigned short*)&l, hs = *(unsigned short*)&h;
    return ((unsigned int)hs << 16) | ls;
}

// v_dot2_f32_bf16: z += lo(w)*lo(h) + hi(w)*hi(h)
#define DOT2(z, w, h) asm("v_dot2_f32_bf16 %0, %1, %2, %0" : "+v"(z) : "v"(w), "v"(h))
// opaque pin: value becomes non-rematerializable
#define PIN4(V_) asm volatile("" : "+v"((V_).x), "+v"((V_).y), "+v"((V_).z), "+v"((V_).w))

// ---------------------------------------------------------------- prep: all weight repacks
// whh pack for 512-thread rec layout: thread u=i*2+p2, slice m2=g*16+kk2 (64 slices x 512 thr x 4 u32)
__global__ void k_prep(const float* __restrict__ whh_f, const float* __restrict__ whh_b,
                       const float* __restrict__ wih_f, const float* __restrict__ wih_b,
                       unsigned int* __restrict__ wp_f, unsigned int* __restrict__ wp_b,
                       unsigned int* __restrict__ wihT2_f, unsigned int* __restrict__ wihT2_b) {
    int blk = blockIdx.x, t = threadIdx.x;
    if (blk < 1024) {
        const float* src   = (blk < 512) ? whh_f : whh_b;
        unsigned int* dst  = (blk < 512) ? wp_f  : wp_b;
        int d = ((blk & 511) << 8) + t;            // u32 index over 1024*128
        int m2 = d >> 11, rem = d & 2047;
        int u = rem >> 2, e2 = rem & 3;
        int i = u >> 1, p2 = u & 1;
        int g = m2 >> 4, kk2 = m2 & 15;
        int col = (g << 8) + i;
        int k = (p2 << 7) + (kk2 << 3) + (e2 << 1);
        float2 sv = *(const float2*)(src + col * 256 + k);
        dst[d] = pack2(sv.x, sv.y);
    } else {
        int id = blk - 1024;
        const float* src  = (id < 256) ? wih_f   : wih_b;
        unsigned int* dst = (id < 256) ? wihT2_f : wihT2_b;
        int d = ((id & 255) << 8) + t;             // u32 index over 64*1024
        int kp = d >> 10, j = d & 1023;
        float2 sv = *(const float2*)(src + j * 128 + 2 * kp);
        dst[d] = pack2(sv.x, sv.y);                // wihT2[kp*1024 + j]
    }
}

// ---------------------------------------------------------------- input proj (DOT2, 32 rows/block, 512 thr)
__global__ void k_input_proj(const int* __restrict__ word_ids,
                             const float* __restrict__ word_emb,
                             const unsigned int* __restrict__ wihT2_f, const float* __restrict__ b_f,
                             const unsigned int* __restrict__ wihT2_b, const float* __restrict__ b_b,
                             bf16* __restrict__ igq_f, bf16* __restrict__ igq_b) {
    int dir = blockIdx.y;
    const unsigned int* wihT2 = dir ? wihT2_b : wihT2_f;
    const float* bb  = dir ? b_b   : b_f;
    bf16* igq        = dir ? igq_b : igq_f;
    __shared__ unsigned int x2[32][64];
    int t  = threadIdx.x;                  // 0..511
    int r0 = blockIdx.x * 32;
    for (int u = t; u < 32 * 64; u += 512) {
        int rr = u >> 6, ep = u & 63;
        int r = r0 + rr;
        int s = r >> 6, b = r & 63;
        int wid = word_ids[b * S_ + s];
        float2 ev = *(const float2*)(word_emb + (size_t)wid * E_ + 2 * ep);
        x2[rr][ep] = pack2(ev.x, ev.y);
    }
    __syncthreads();
    int j = t & 255, jh = t >> 8;          // thread covers cj = 2jh, 2jh+1
    float acc[2][32];
    #pragma unroll
    for (int c2 = 0; c2 < 2; ++c2) {
        float bv = bb[j + (2 * jh + c2) * 256];
        #pragma unroll
        for (int rr = 0; rr < 32; ++rr) acc[c2][rr] = bv;
    }
    for (int kp = 0; kp < 64; ++kp) {
        unsigned int wv0 = wihT2[kp * 1024 + j + (2 * jh) * 256];
        unsigned int wv1 = wihT2[kp * 1024 + j + (2 * jh + 1) * 256];
        #pragma unroll
        for (int rr = 0; rr < 32; ++rr) {
            unsigned int xp = x2[rr][kp];
            DOT2(acc[0][rr], wv0, xp);
            DOT2(acc[1][rr], wv1, xp);
        }
    }
    #pragma unroll
    for (int rr = 0; rr < 32; ++rr)
        *(unsigned int*)(igq + (size_t)(r0 + rr) * 1024 + j * 4 + 2 * jh) =
            pack2(acc[0][rr], acc[1][rr]);
}

// ---------------------------------------------------------------- fused recurrence + char CNN
// 512 threads, 2 waves/SIMD. Weights: m2=0..55 pinned (AGPR side), m2=56..63 LDS.
__global__ __launch_bounds__(512, 2) void k_lstm_cnn(
        const bf16* __restrict__ igq_f, const bf16* __restrict__ igq_b,
        const uint4* __restrict__ wp_f, const uint4* __restrict__ wp_b,
        unsigned int* __restrict__ hfp, unsigned int* __restrict__ hbp,
        const int* __restrict__ char_ids, const float* __restrict__ char_emb,
        const float* __restrict__ cnn_w, const float* __restrict__ cnn_b,
        float* __restrict__ out_char) {
    __shared__ uint4 wlds[9216];                          // 144 KiB pool (rec uses 64 KiB)
    __shared__ __align__(16) unsigned int hpbuf[2][160];

    int t = threadIdx.x;

    if (blockIdx.x < 128) {
        // ======================= LSTM recurrence ==========================
        int b   = blockIdx.x & 63;
        int dir = blockIdx.x >> 6;
        const bf16* igq  = dir ? igq_b : igq_f;
        const uint4* wp  = dir ? wp_b  : wp_f;
        unsigned int* hs = dir ? hbp   : hfp;

        int i = t >> 1, p2 = t & 1;

        for (int v = t; v < 4096; v += 512) wlds[v] = wp[56 * 512 + v];
        if (t < 320) ((unsigned int*)hpbuf)[t] = 0;
        float c_reg = 0.f;

        uint4 wreg[56];
        #pragma unroll
        for (int m = 0; m < 56; ++m) {
            wreg[m] = wp[m * 512 + t];
            PIN4(wreg[m]);
        }
        __syncthreads();

        int cur = 0;
        int s0 = dir ? (S_ - 1) : 0;
        uint2 igu = *(const uint2*)&igq[((size_t)s0 * B_ + b) * 1024 + i * 4];

        for (int step = 0; step < S_; ++step) {
            int s = dir ? (S_ - 1 - step) : step;

            float z0 = 0.f, z1 = 0.f, z2 = 0.f, z3 = 0.f;
            if (p2 == 0) {
                z0 = __uint_as_float(igu.x << 16);
                z1 = __uint_as_float(igu.x & 0xffff0000u);
                z2 = __uint_as_float(igu.y << 16);
                z3 = __uint_as_float(igu.y & 0xffff0000u);
            }
            const char* hpc = (const char*)hpbuf[cur];
            #pragma unroll
            for (int kk = 0; kk < 16; ++kk) {
                uint4 hv = *(const uint4*)(hpc + (p2 * 2 + (kk >> 3)) * 144 + (kk & 7) * 16);
                {   uint4 wv = wreg[kk];
                    DOT2(z0, wv.x, hv.x); DOT2(z0, wv.y, hv.y);
                    DOT2(z0, wv.z, hv.z); DOT2(z0, wv.w, hv.w); }
                {   uint4 wv = wreg[16 + kk];
                    DOT2(z1, wv.x, hv.x); DOT2(z1, wv.y, hv.y);
                    DOT2(z1, wv.z, hv.z); DOT2(z1, wv.w, hv.w); }
                {   uint4 wv = wreg[32 + kk];
                    DOT2(z2, wv.x, hv.x); DOT2(z2, wv.y, hv.y);
                    DOT2(z2, wv.z, hv.z); DOT2(z2, wv.w, hv.w); }
                {   uint4 wv = (kk < 8) ? wreg[48 + kk] : wlds[(kk - 8) * 512 + t];
                    DOT2(z3, wv.x, hv.x); DOT2(z3, wv.y, hv.y);
                    DOT2(z3, wv.z, hv.z); DOT2(z3, wv.w, hv.w); }
            }
            if (step + 1 < S_) {
                int sn = dir ? (S_ - 2 - step) : (step + 1);
                igu = *(const uint2*)&igq[((size_t)sn * B_ + b) * 1024 + i * 4];
            }
            // butterfly over p2 only (lanes differing in bit 0)
            z0 += __shfl_xor(z0, 1);
            z1 += __shfl_xor(z1, 1);
            z2 += __shfl_xor(z2, 1);
            z3 += __shfl_xor(z3, 1);
            if (p2 == 0) {
                float si = fast_sigmoid(z0);
                float sf = fast_sigmoid(z1);
                float tg = fast_tanh(z2);
                float so = fast_sigmoid(z3);
                c_reg = sf * c_reg + si * tg;
                float hn = so * fast_tanh(c_reg);
                char* dstb = (char*)hpbuf[cur ^ 1] + (i >> 6) * 144 + ((i >> 1) & 31) * 4 + (i & 1) * 2;
                *(bf16*)dstb = f2b(hn);
            }
            __syncthreads();
            // export packed h (this step) to global, coalesced u32 stores
            if (t < 128) {
                hs[((size_t)s * B_ + b) * 128 + t] =
                    hpbuf[cur ^ 1][(t >> 5) * 36 + (t & 31)];
            }
            cur ^= 1;
        }
    } else {
        // ======================= char CNN on idle CUs ======================
        unsigned int* pool_u = (unsigned int*)wlds;
        float*        pool_f = (float*)wlds;
        int blkc = blockIdx.x - 128;

        for (int u = t; u < 4 * 192; u += 512) {
            int c = u / 192, pe = u % 192;
            pool_u[c * 196 + pe] = pack2(cnn_w[c * 384 + 2 * pe], cnn_w[c * 384 + 2 * pe + 1]);
        }
        if (t < 4) pool_f[784 + t] = cnn_b[t];
        __syncthreads();

        int wv = t >> 6, lane = t & 63;          // 8 waves
        unsigned int* cew = pool_u + 800 + wv * 1224;
        int pos = lane >> 2, c = lane & 3;

        #pragma unroll 1
        for (int j = 0; j < 8; ++j) {            // 8 words per wave
            int word = (blkc * 8 + wv) * 8 + j;
            const int* ids = char_ids + word * WP_;
            for (int row = 0; row < WP_; ++row) {
                float2 ev = *(const float2*)(char_emb + (size_t)ids[row] * 128 + 2 * lane);
                cew[row * 68 + lane] = pack2(ev.x, ev.y);
            }
            float acc = 0.f;
            #pragma unroll
            for (int i = 0; i < K_; ++i) {
                const uint4* cr = (const uint4*)(cew + (pos + i) * 68);
                const uint4* wr = (const uint4*)(pool_u + c * 196 + i * 64);
                #pragma unroll
                for (int q = 0; q < 16; ++q) {
                    uint4 cv = cr[q], wq = wr[q];
                    DOT2(acc, wq.x, cv.x); DOT2(acc, wq.y, cv.y);
                    DOT2(acc, wq.z, cv.z); DOT2(acc, wq.w, cv.w);
                }
            }
            acc += pool_f[784 + c];
            #pragma unroll
            for (int off = 4; off < 64; off <<= 1) acc = fmaxf(acc, __shfl_xor(acc, off));
            if (lane < L_) out_char[(size_t)word * L_ + lane] = acc;
        }
    }
}

// ---------------------------------------------------------------- fused tag linear + log_softmax
// one block per batch b. FIXED lane mapping (round 20 had it swapped -> 1e8 bank
// conflicts): sl = u>>6 is WAVE-UNIFORM (hv row broadcast), tt = u&63 is PER-LANE
// (ow stride 257, conflict-free), matching the proven k_tag_linear pattern.
__global__ __launch_bounds__(1024) void k_tag_sm(
        const unsigned int* __restrict__ hfp, const unsigned int* __restrict__ hbp,
        const float* __restrict__ out_w, const float* __restrict__ out_b,
        float* __restrict__ out) {
    __shared__ unsigned int ow[50 * 257];      // 51400 B
    __shared__ unsigned int hv[64][256];       // 65536 B
    __shared__ float tb[50][128];              // 25600 B
    int b = blockIdx.x;
    int t = threadIdx.x;                       // 0..1023

    for (int u = t; u < 12800; u += 1024) {
        int tt = u >> 8, kp = u & 255;
        float2 wv = *(const float2*)(out_w + tt * 512 + 2 * kp);
        ow[tt * 257 + kp] = pack2(wv.x, wv.y);
    }

    for (int chunk = 0; chunk < 2; ++chunk) {
        int sbase = chunk * 64;
        __syncthreads();                       // hv safe to overwrite (and ow ready, 1st iter)
        for (int u = t; u < 64 * 256; u += 1024) {
            int sl = u >> 8, q = u & 255;
            int s = sbase + sl;
            const unsigned int* src = (q < 128) ? hfp : hbp;
            hv[sl][q] = src[((size_t)s * B_ + b) * 128 + (q & 127)];
        }
        __syncthreads();
        for (int u = t; u < 64 * 64; u += 1024) {
            int sl = u >> 6;                   // wave-uniform -> hv row broadcast
            int tt = u & 63;                   // per-lane -> ow stride 257 (pad)
            if (tt < T_) {
                float acc = out_b[tt];
                const unsigned int* owr = &ow[tt * 257];
                const unsigned int* hvr = hv[sl];
                #pragma unroll 8
                for (int kp = 0; kp < 256; ++kp) DOT2(acc, owr[kp], hvr[kp]);
                tb[tt][sbase + sl] = acc;
            }
        }
    }
    __syncthreads();

    // log_softmax over s (axis=1): 16 waves cover 50 t-rows
    int wv = t >> 6, lane = t & 63;
    for (int row = wv; row < T_; row += 16) {
        float v0 = tb[row][lane], v1 = tb[row][lane + 64];
        float m = fmaxf(v0, v1);
        #pragma unroll
        for (int off = 32; off; off >>= 1) m = fmaxf(m, __shfl_xor(m, off));
        float e = expf(v0 - m) + expf(v1 - m);
        #pragma unroll
        for (int off = 32; off; off >>= 1) e += __shfl_xor(e, off);
        float lse = m + logf(e);
        out[((size_t)b * S_ + lane)      * T_ + row] = v0 - lse;
        out[((size_t)b * S_ + lane + 64) * T_ + row] = v1 - lse;
    }
}

// ---------------------------------------------------------------- launch
extern "C" void kernel_launch(void* const* d_in, const int* in_sizes, int n_in,
                              void* d_out, int out_size, void* d_ws, size_t ws_size,
                              hipStream_t stream) {
    const int*   char_ids = (const int*)d_in[0];
    const int*   word_ids = (const int*)d_in[1];
    const float* char_emb = (const float*)d_in[2];
    const float* word_emb = (const float*)d_in[3];
    const float* cnn_w    = (const float*)d_in[4];
    const float* cnn_b    = (const float*)d_in[5];
    const float* wih_f    = (const float*)d_in[6];
    const float* whh_f    = (const float*)d_in[7];
    const float* b_f      = (const float*)d_in[8];
    const float* wih_b    = (const float*)d_in[9];
    const float* whh_b    = (const float*)d_in[10];
    const float* b_b      = (const float*)d_in[11];
    const float* out_w    = (const float*)d_in[12];
    const float* out_b    = (const float*)d_in[13];
    float* out = (float*)d_out;
    char* ws   = (char*)d_ws;

    size_t o = 0;
    unsigned int* wihT2_f = (unsigned int*)(ws + o); o += (size_t)64 * 1024 * 4;
    unsigned int* wihT2_b = (unsigned int*)(ws + o); o += (size_t)64 * 1024 * 4;
    unsigned int* wp_f    = (unsigned int*)(ws + o); o += (size_t)1024 * 128 * 4;
    unsigned int* wp_b    = (unsigned int*)(ws + o); o += (size_t)1024 * 128 * 4;
    bf16* igq_f  = (bf16*)(ws + o); o += (size_t)S_ * B_ * 1024 * 2;
    bf16* igq_b  = (bf16*)(ws + o); o += (size_t)S_ * B_ * 1024 * 2;
    unsigned int* hfp = (unsigned int*)(ws + o); o += (size_t)S_ * B_ * 128 * 4;
    unsigned int* hbp = (unsigned int*)(ws + o); o += (size_t)S_ * B_ * 128 * 4;

    k_prep<<<1536, 256, 0, stream>>>(whh_f, whh_b, wih_f, wih_b,
                                     wp_f, wp_b, wihT2_f, wihT2_b);
    k_input_proj<<<dim3(256, 2), 512, 0, stream>>>(word_ids, word_emb,
                                                   wihT2_f, b_f, wihT2_b, b_b, igq_f, igq_b);
    k_lstm_cnn<<<256, 512, 0, stream>>>(igq_f, igq_b,
                                        (const uint4*)wp_f, (const uint4*)wp_b, hfp, hbp,
                                        char_ids, char_emb, cnn_w, cnn_b,
                                        out + (size_t)B_ * S_ * T_);
    k_tag_sm<<<B_, 1024, 0, stream>>>(hfp, hbp, out_w, out_b, out);
}

// Round 22
// 333.665 us; speedup vs baseline: 3.0932x; 1.1594x over previous
//
#include <hip/hip_runtime.h>
#include <hip/hip_bf16.h>

#define B_  64
#define S_  128
#define WP_ 18
#define K_  3
#define E_  128
#define H_  256
#define L_  4
#define T_  50

typedef __hip_bfloat16 bf16;

__device__ __forceinline__ float b2f(bf16 x) { return __bfloat162float(x); }
__device__ __forceinline__ bf16  f2b(float x) { return __float2bfloat16(x); }

__device__ __forceinline__ float fast_sigmoid(float x) {
    return 1.f / (1.f + __expf(-x));
}
__device__ __forceinline__ float fast_tanh(float x) {
    float a = fminf(fmaxf(2.f * x, -30.f), 30.f);
    float e = __expf(a);
    return (e - 1.f) / (e + 1.f);
}
__device__ __forceinline__ unsigned int pack2(float lo, float hi) {
    bf16 l = f2b(lo), h = f2b(hi);
    unsigned short ls = *(unsigned short*)&l, hs = *(unsigned short*)&h;
    return ((unsigned int)hs << 16) | ls;
}

// v_dot2_f32_bf16: z += lo(w)*lo(h) + hi(w)*hi(h)
#define DOT2(z, w, h) asm("v_dot2_f32_bf16 %0, %1, %2, %0" : "+v"(z) : "v"(w), "v"(h))
// opaque pin: value becomes non-rematerializable
#define PIN4(V_) asm volatile("" : "+v"((V_).x), "+v"((V_).y), "+v"((V_).z), "+v"((V_).w))

// ---------------------------------------------------------------- prep: all weight repacks
// whh pack for 512-thread rec layout: thread u=i*2+p2, slice m2=g*16+kk2 (64 slices x 512 thr x 4 u32)
__global__ void k_prep(const float* __restrict__ whh_f, const float* __restrict__ whh_b,
                       const float* __restrict__ wih_f, const float* __restrict__ wih_b,
                       unsigned int* __restrict__ wp_f, unsigned int* __restrict__ wp_b,
                       unsigned int* __restrict__ wihT2_f, unsigned int* __restrict__ wihT2_b) {
    int blk = blockIdx.x, t = threadIdx.x;
    if (blk < 1024) {
        const float* src   = (blk < 512) ? whh_f : whh_b;
        unsigned int* dst  = (blk < 512) ? wp_f  : wp_b;
        int d = ((blk & 511) << 8) + t;            // u32 index over 1024*128
        int m2 = d >> 11, rem = d & 2047;
        int u = rem >> 2, e2 = rem & 3;
        int i = u >> 1, p2 = u & 1;
        int g = m2 >> 4, kk2 = m2 & 15;
        int col = (g << 8) + i;
        int k = (p2 << 7) + (kk2 << 3) + (e2 << 1);
        float2 sv = *(const float2*)(src + col * 256 + k);
        dst[d] = pack2(sv.x, sv.y);
    } else {
        int id = blk - 1024;
        const float* src  = (id < 256) ? wih_f   : wih_b;
        unsigned int* dst = (id < 256) ? wihT2_f : wihT2_b;
        int d = ((id & 255) << 8) + t;             // u32 index over 64*1024
        int kp = d >> 10, j = d & 1023;
        float2 sv = *(const float2*)(src + j * 128 + 2 * kp);
        dst[d] = pack2(sv.x, sv.y);                // wihT2[kp*1024 + j]
    }
}

// ---------------------------------------------------------------- input proj (DOT2, 32 rows/block, 512 thr)
__global__ void k_input_proj(const int* __restrict__ word_ids,
                             const float* __restrict__ word_emb,
                             const unsigned int* __restrict__ wihT2_f, const float* __restrict__ b_f,
                             const unsigned int* __restrict__ wihT2_b, const float* __restrict__ b_b,
                             bf16* __restrict__ igq_f, bf16* __restrict__ igq_b) {
    int dir = blockIdx.y;
    const unsigned int* wihT2 = dir ? wihT2_b : wihT2_f;
    const float* bb  = dir ? b_b   : b_f;
    bf16* igq        = dir ? igq_b : igq_f;
    __shared__ unsigned int x2[32][64];
    int t  = threadIdx.x;                  // 0..511
    int r0 = blockIdx.x * 32;
    for (int u = t; u < 32 * 64; u += 512) {
        int rr = u >> 6, ep = u & 63;
        int r = r0 + rr;
        int s = r >> 6, b = r & 63;
        int wid = word_ids[b * S_ + s];
        float2 ev = *(const float2*)(word_emb + (size_t)wid * E_ + 2 * ep);
        x2[rr][ep] = pack2(ev.x, ev.y);
    }
    __syncthreads();
    int j = t & 255, jh = t >> 8;          // thread covers cj = 2jh, 2jh+1
    float acc[2][32];
    #pragma unroll
    for (int c2 = 0; c2 < 2; ++c2) {
        float bv = bb[j + (2 * jh + c2) * 256];
        #pragma unroll
        for (int rr = 0; rr < 32; ++rr) acc[c2][rr] = bv;
    }
    for (int kp = 0; kp < 64; ++kp) {
        unsigned int wv0 = wihT2[kp * 1024 + j + (2 * jh) * 256];
        unsigned int wv1 = wihT2[kp * 1024 + j + (2 * jh + 1) * 256];
        #pragma unroll
        for (int rr = 0; rr < 32; ++rr) {
            unsigned int xp = x2[rr][kp];
            DOT2(acc[0][rr], wv0, xp);
            DOT2(acc[1][rr], wv1, xp);
        }
    }
    #pragma unroll
    for (int rr = 0; rr < 32; ++rr)
        *(unsigned int*)(igq + (size_t)(r0 + rr) * 1024 + j * 4 + 2 * jh) =
            pack2(acc[0][rr], acc[1][rr]);
}

// ---------------------------------------------------------------- fused recurrence + char CNN
// 512 threads, 2 waves/SIMD. Thread u = i*2 + p2 covers unit i's 4 gate columns
// over k in [128*p2, 128*p2+128).
// Weights: m2=0..55 pinned in 224 regs (AGPR side), m2=56..63 in LDS (64 KB).
// 64-slice full pin SPILLS (round 19: +scratch traffic, 454 us) — 56 is the max.
__global__ __launch_bounds__(512, 2) void k_lstm_cnn(
        const bf16* __restrict__ igq_f, const bf16* __restrict__ igq_b,
        const uint4* __restrict__ wp_f, const uint4* __restrict__ wp_b,
        unsigned int* __restrict__ hfp, unsigned int* __restrict__ hbp,
        const int* __restrict__ char_ids, const float* __restrict__ char_emb,
        const float* __restrict__ cnn_w, const float* __restrict__ cnn_b,
        float* __restrict__ out_char) {
    __shared__ uint4 wlds[9216];                          // 144 KiB pool (rec uses 64 KiB)
    __shared__ __align__(16) unsigned int hpbuf[2][160];

    int t = threadIdx.x;

    if (blockIdx.x < 128) {
        // ======================= LSTM recurrence ==========================
        int b   = blockIdx.x & 63;
        int dir = blockIdx.x >> 6;
        const bf16* igq  = dir ? igq_b : igq_f;
        const uint4* wp  = dir ? wp_b  : wp_f;
        unsigned int* hs = dir ? hbp   : hfp;

        int i = t >> 1, p2 = t & 1;

        for (int v = t; v < 4096; v += 512) wlds[v] = wp[56 * 512 + v];
        if (t < 320) ((unsigned int*)hpbuf)[t] = 0;
        float c_reg = 0.f;

        uint4 wreg[56];
        #pragma unroll
        for (int m = 0; m < 56; ++m) {
            wreg[m] = wp[m * 512 + t];
            PIN4(wreg[m]);
        }
        __syncthreads();

        int cur = 0;
        int s0 = dir ? (S_ - 1) : 0;
        uint2 igu = *(const uint2*)&igq[((size_t)s0 * B_ + b) * 1024 + i * 4];

        for (int step = 0; step < S_; ++step) {
            int s = dir ? (S_ - 1 - step) : step;

            float z0 = 0.f, z1 = 0.f, z2 = 0.f, z3 = 0.f;
            if (p2 == 0) {
                z0 = __uint_as_float(igu.x << 16);
                z1 = __uint_as_float(igu.x & 0xffff0000u);
                z2 = __uint_as_float(igu.y << 16);
                z3 = __uint_as_float(igu.y & 0xffff0000u);
            }
            const char* hpc = (const char*)hpbuf[cur];
            #pragma unroll
            for (int kk = 0; kk < 16; ++kk) {
                uint4 hv = *(const uint4*)(hpc + (p2 * 2 + (kk >> 3)) * 144 + (kk & 7) * 16);
                {   uint4 wv = wreg[kk];
                    DOT2(z0, wv.x, hv.x); DOT2(z0, wv.y, hv.y);
                    DOT2(z0, wv.z, hv.z); DOT2(z0, wv.w, hv.w); }
                {   uint4 wv = wreg[16 + kk];
                    DOT2(z1, wv.x, hv.x); DOT2(z1, wv.y, hv.y);
                    DOT2(z1, wv.z, hv.z); DOT2(z1, wv.w, hv.w); }
                {   uint4 wv = wreg[32 + kk];
                    DOT2(z2, wv.x, hv.x); DOT2(z2, wv.y, hv.y);
                    DOT2(z2, wv.z, hv.z); DOT2(z2, wv.w, hv.w); }
                {   uint4 wv = (kk < 8) ? wreg[48 + kk] : wlds[(kk - 8) * 512 + t];
                    DOT2(z3, wv.x, hv.x); DOT2(z3, wv.y, hv.y);
                    DOT2(z3, wv.z, hv.z); DOT2(z3, wv.w, hv.w); }
            }
            if (step + 1 < S_) {
                int sn = dir ? (S_ - 2 - step) : (step + 1);
                igu = *(const uint2*)&igq[((size_t)sn * B_ + b) * 1024 + i * 4];
            }
            // butterfly over p2 only (lanes differing in bit 0)
            z0 += __shfl_xor(z0, 1);
            z1 += __shfl_xor(z1, 1);
            z2 += __shfl_xor(z2, 1);
            z3 += __shfl_xor(z3, 1);
            if (p2 == 0) {
                float si = fast_sigmoid(z0);
                float sf = fast_sigmoid(z1);
                float tg = fast_tanh(z2);
                float so = fast_sigmoid(z3);
                c_reg = sf * c_reg + si * tg;
                float hn = so * fast_tanh(c_reg);
                char* dstb = (char*)hpbuf[cur ^ 1] + (i >> 6) * 144 + ((i >> 1) & 31) * 4 + (i & 1) * 2;
                *(bf16*)dstb = f2b(hn);
            }
            __syncthreads();
            // export packed h (this step) to global, coalesced u32 stores
            if (t < 128) {
                hs[((size_t)s * B_ + b) * 128 + t] =
                    hpbuf[cur ^ 1][(t >> 5) * 36 + (t & 31)];
            }
            cur ^= 1;
        }
    } else {
        // ======================= char CNN on idle CUs ======================
        unsigned int* pool_u = (unsigned int*)wlds;
        float*        pool_f = (float*)wlds;
        int blkc = blockIdx.x - 128;

        for (int u = t; u < 4 * 192; u += 512) {
            int c = u / 192, pe = u % 192;
            pool_u[c * 196 + pe] = pack2(cnn_w[c * 384 + 2 * pe], cnn_w[c * 384 + 2 * pe + 1]);
        }
        if (t < 4) pool_f[784 + t] = cnn_b[t];
        __syncthreads();

        int wv = t >> 6, lane = t & 63;          // 8 waves
        unsigned int* cew = pool_u + 800 + wv * 1224;
        int pos = lane >> 2, c = lane & 3;

        #pragma unroll 1
        for (int j = 0; j < 8; ++j) {            // 8 words per wave
            int word = (blkc * 8 + wv) * 8 + j;
            const int* ids = char_ids + word * WP_;
            for (int row = 0; row < WP_; ++row) {
                float2 ev = *(const float2*)(char_emb + (size_t)ids[row] * 128 + 2 * lane);
                cew[row * 68 + lane] = pack2(ev.x, ev.y);
            }
            float acc = 0.f;
            #pragma unroll
            for (int i = 0; i < K_; ++i) {
                const uint4* cr = (const uint4*)(cew + (pos + i) * 68);
                const uint4* wr = (const uint4*)(pool_u + c * 196 + i * 64);
                #pragma unroll
                for (int q = 0; q < 16; ++q) {
                    uint4 cv = cr[q], wq = wr[q];
                    DOT2(acc, wq.x, cv.x); DOT2(acc, wq.y, cv.y);
                    DOT2(acc, wq.z, cv.z); DOT2(acc, wq.w, cv.w);
                }
            }
            acc += pool_f[784 + c];
            #pragma unroll
            for (int off = 4; off < 64; off <<= 1) acc = fmaxf(acc, __shfl_xor(acc, off));
            if (lane < L_) out_char[(size_t)word * L_ + lane] = acc;
        }
    }
}

// ---------------------------------------------------------------- tag linear (16 words/block, packed h)
__global__ __launch_bounds__(1024) void k_tag_linear(
        const unsigned int* __restrict__ hfp, const unsigned int* __restrict__ hbp,
        const float* __restrict__ out_w, const float* __restrict__ out_b,
        float* __restrict__ tag) {
    __shared__ unsigned int ow[50 * 257];      // 51400 B
    __shared__ unsigned int hv[16][256];       // 16384 B
    int bs0 = blockIdx.x * 16;
    int t = threadIdx.x;                       // 0..1023
    for (int u = t; u < 12800; u += 1024) {
        int tt = u >> 8, kp = u & 255;
        float2 wv = *(const float2*)(out_w + tt * 512 + 2 * kp);
        ow[tt * 257 + kp] = pack2(wv.x, wv.y);
    }
    for (int u = t; u < 16 * 256; u += 1024) {
        int w = u >> 8, q = u & 255;
        int bs = bs0 + w;
        int b = bs >> 7, s = bs & 127;
        const unsigned int* src = (q < 128) ? hfp : hbp;
        hv[w][q] = src[((size_t)s * B_ + b) * 128 + (q & 127)];
    }
    __syncthreads();
    int w = t >> 6, tt = t & 63;
    if (tt < T_) {
        int bs = bs0 + w;
        int b = bs >> 7, s = bs & 127;
        float acc = out_b[tt];
        const unsigned int* owr = &ow[tt * 257];
        const unsigned int* hvr = hv[w];
        #pragma unroll 8
        for (int kp = 0; kp < 256; ++kp) DOT2(acc, owr[kp], hvr[kp]);
        tag[((size_t)b * T_ + tt) * S_ + s] = acc;
    }
}

// ---------------------------------------------------------------- log_softmax over S (axis=1)
__global__ void k_log_softmax(const float* __restrict__ tag, float* __restrict__ out) {
    int wid  = (blockIdx.x * 256 + threadIdx.x) >> 6;
    int lane = threadIdx.x & 63;
    if (wid >= B_ * T_) return;
    int b = wid / T_, t = wid % T_;
    const float* row = tag + (size_t)wid * S_;
    float v0 = row[lane], v1 = row[lane + 64];
    float m = fmaxf(v0, v1);
    #pragma unroll
    for (int off = 32; off; off >>= 1) m = fmaxf(m, __shfl_xor(m, off));
    float e = expf(v0 - m) + expf(v1 - m);
    #pragma unroll
    for (int off = 32; off; off >>= 1) e += __shfl_xor(e, off);
    float lse = m + logf(e);
    out[((size_t)b * S_ + lane)      * T_ + t] = v0 - lse;
    out[((size_t)b * S_ + lane + 64) * T_ + t] = v1 - lse;
}

// ---------------------------------------------------------------- launch
extern "C" void kernel_launch(void* const* d_in, const int* in_sizes, int n_in,
                              void* d_out, int out_size, void* d_ws, size_t ws_size,
                              hipStream_t stream) {
    const int*   char_ids = (const int*)d_in[0];
    const int*   word_ids = (const int*)d_in[1];
    const float* char_emb = (const float*)d_in[2];
    const float* word_emb = (const float*)d_in[3];
    const float* cnn_w    = (const float*)d_in[4];
    const float* cnn_b    = (const float*)d_in[5];
    const float* wih_f    = (const float*)d_in[6];
    const float* whh_f    = (const float*)d_in[7];
    const float* b_f      = (const float*)d_in[8];
    const float* wih_b    = (const float*)d_in[9];
    const float* whh_b    = (const float*)d_in[10];
    const float* b_b      = (const float*)d_in[11];
    const float* out_w    = (const float*)d_in[12];
    const float* out_b    = (const float*)d_in[13];
    float* out = (float*)d_out;
    char* ws   = (char*)d_ws;

    size_t o = 0;
    unsigned int* wihT2_f = (unsigned int*)(ws + o); o += (size_t)64 * 1024 * 4;
    unsigned int* wihT2_b = (unsigned int*)(ws + o); o += (size_t)64 * 1024 * 4;
    unsigned int* wp_f    = (unsigned int*)(ws + o); o += (size_t)1024 * 128 * 4;
    unsigned int* wp_b    = (unsigned int*)(ws + o); o += (size_t)1024 * 128 * 4;
    bf16* igq_f  = (bf16*)(ws + o); o += (size_t)S_ * B_ * 1024 * 2;
    bf16* igq_b  = (bf16*)(ws + o); o += (size_t)S_ * B_ * 1024 * 2;
    unsigned int* hfp = (unsigned int*)(ws + o); o += (size_t)S_ * B_ * 128 * 4;
    unsigned int* hbp = (unsigned int*)(ws + o); o += (size_t)S_ * B_ * 128 * 4;
    float* tag   = (float*)(ws + o); o += (size_t)B_ * T_ * S_ * 4;

    k_prep<<<1536, 256, 0, stream>>>(whh_f, whh_b, wih_f, wih_b,
                                     wp_f, wp_b, wihT2_f, wihT2_b);
    k_input_proj<<<dim3(256, 2), 512, 0, stream>>>(word_ids, word_emb,
                                                   wihT2_f, b_f, wihT2_b, b_b, igq_f, igq_b);
    k_lstm_cnn<<<256, 512, 0, stream>>>(igq_f, igq_b,
                                        (const uint4*)wp_f, (const uint4*)wp_b, hfp, hbp,
                                        char_ids, char_emb, cnn_w, cnn_b,
                                        out + (size_t)B_ * S_ * T_);
    k_tag_linear<<<B_ * S_ / 16, 1024, 0, stream>>>(hfp, hbp, out_w, out_b, tag);
    k_log_softmax<<<(B_ * T_ + 3) / 4, 256, 0, stream>>>(tag, out);
}